// Round 1
// baseline (398.385 us; speedup 1.0000x reference)
//
#include <hip/hip_runtime.h>

// DifferentiableEKF: B=8192 independent 2-state Kalman chains, T=2048 sequential steps.
// One thread per batch row; 5-float state (P stays symmetric); float4-streamed inputs
// with an 8-chunk register prefetch pipeline; packed float4 output stores.

#define NB 8192
#define NT 2048
#define PD 8   // prefetch distance in chunks (4 steps/chunk)

__device__ __forceinline__ float fast_rcp(float x) { return __builtin_amdgcn_rcpf(x); }

__device__ __forceinline__ void ekf_step(float z, float h, float s,
                                         float& x0, float& x1,
                                         float& p00, float& p01, float& p11)
{
    // a = dt*rho, dt=1, rho = 0.5 + 0.5*sigmoid(10h-5)
    // exp(-(10h-5)) = exp2(fma(h, -10*log2e, 5*log2e))
    float e  = __builtin_amdgcn_exp2f(__builtin_fmaf(h, -14.4269504088896f, 7.2134752044448f));
    float a  = __builtin_fmaf(0.5f, fast_rcp(1.0f + e), 0.5f);
    float scale = fmaxf(s * 100.0f, 1.0f);
    float q  = scale * 0.1f;
    float rp = scale + 1e-6f;                         // R + eps folded
    float qr = q + rp;
    float two_a = a + a;
    float a2 = a * a;

    // P_pred (symmetric): pp00 = p00 + 2a*p01 + a^2*p11 + q ; pp01 = p01 + a*p11 ; pp11 = p11 + q
    // Compute Seff = pp00 + rp first so rcp starts early on the critical path.
    float tA   = __builtin_fmaf(two_a, p01, p00);
    float tB   = __builtin_fmaf(a2, p11, qr);
    float Seff = tA + tB;                              // pp00 + scale + 1e-6
    float Sinv = fast_rcp(Seff);
    float pp00 = Seff - rp;
    float pp01 = __builtin_fmaf(a, p11, p01);
    float pp11 = p11 + q;

    float K0 = pp00 * Sinv;
    float K1 = pp01 * Sinv;

    float xp0 = __builtin_fmaf(a, x1, x0);             // x_pred[0]; x_pred[1] = x1
    float y   = z - xp0;
    x0 = __builtin_fmaf(K0, y, xp0);
    x1 = __builtin_fmaf(K1, y, x1);

    p00 = __builtin_fmaf(-K0, pp00, pp00);             // (1-K0)*pp00
    p01 = __builtin_fmaf(-K0, pp01, pp01);             // (1-K0)*pp01
    p11 = __builtin_fmaf(-K1, pp01, pp11);             // pp11 - K1*pp01
}

__global__ __launch_bounds__(64)
void ekf_kernel(const float* __restrict__ price,
                const float* __restrict__ hurst,
                const float* __restrict__ sigv,
                float* __restrict__ out)
{
    const int b = blockIdx.x * 64 + threadIdx.x;       // grid is exactly NB threads

    const float4* __restrict__ pr = (const float4*)(price + (size_t)b * NT);
    const float4* __restrict__ hu = (const float4*)(hurst + (size_t)b * NT);
    const float4* __restrict__ sg = (const float4*)(sigv  + (size_t)b * NT);
    float4* __restrict__ op = (float4*)(out + (size_t)b * (size_t)NT * 2);

    // Prime the software pipeline: PD chunks of 4 timesteps each.
    float4 bp[PD], bh[PD], bs[PD];
#pragma unroll
    for (int i = 0; i < PD; ++i) { bp[i] = pr[i]; bh[i] = hu[i]; bs[i] = sg[i]; }

    // init state: x = [price0, price1 - price0], P = I
    float x0 = bp[0].x;
    float x1 = bp[0].y - bp[0].x;
    float p00 = 1.0f, p01 = 0.0f, p11 = 1.0f;

    const int NC = NT / 4;                              // 512 chunks
    for (int cb = 0; cb < NC; cb += PD) {
#pragma unroll
        for (int j = 0; j < PD; ++j) {
            const int c = cb + j;
            float4 z4 = bp[j], h4 = bh[j], s4 = bs[j];

            // prefetch chunk c+PD into this slot (clamped re-read at the tail)
            int cn = c + PD; if (cn >= NC) cn = NC - 1;
            bp[j] = pr[cn]; bh[j] = hu[cn]; bs[j] = sg[cn];

            float4 o0, o1;
            ekf_step(z4.x, h4.x, s4.x, x0, x1, p00, p01, p11); o0.x = x0; o0.y = x1;
            ekf_step(z4.y, h4.y, s4.y, x0, x1, p00, p01, p11); o0.z = x0; o0.w = x1;
            ekf_step(z4.z, h4.z, s4.z, x0, x1, p00, p01, p11); o1.x = x0; o1.y = x1;
            ekf_step(z4.w, h4.w, s4.w, x0, x1, p00, p01, p11); o1.z = x0; o1.w = x1;

            op[2 * c]     = o0;
            op[2 * c + 1] = o1;
        }
    }
}

extern "C" void kernel_launch(void* const* d_in, const int* in_sizes, int n_in,
                              void* d_out, int out_size, void* d_ws, size_t ws_size,
                              hipStream_t stream)
{
    const float* price = (const float*)d_in[0];
    const float* hurst = (const float*)d_in[1];
    const float* sigv  = (const float*)d_in[2];
    float* out = (float*)d_out;

    dim3 grid(NB / 64), block(64);
    hipLaunchKernelGGL(ekf_kernel, grid, block, 0, stream, price, hurst, sigv, out);
}